// Round 6
// baseline (197.536 us; speedup 1.0000x reference)
//
#include <hip/hip_runtime.h>

#define NN 20000      // nodes
#define NPG 1000      // nodes per graph
#define NBG 20        // graphs
#define DD 128        // feature dim
#define KK2 256       // concat dim
#define KPC 50        // clusters per graph
#define KPAD 64       // padded cluster cols
#define NAC 1000      // total clusters
#define NACP 1024     // padded cluster cols
#define NEDGE 640000
#define CAP 96        // bucket capacity per node (mean deg 32, +11 sigma)

typedef __attribute__((ext_vector_type(8))) short bfrag;      // 8 bf16
typedef __attribute__((ext_vector_type(4))) float f32x4;
typedef __attribute__((ext_vector_type(8))) unsigned short ushort8;
typedef __attribute__((ext_vector_type(8))) _Float16 half8;

__device__ __forceinline__ unsigned short f2bf(float f) {
  unsigned int u = __builtin_bit_cast(unsigned int, f);
  unsigned int r = (u + 0x7FFFu + ((u >> 16) & 1u)) >> 16;   // RNE
  return (unsigned short)r;
}
__device__ __forceinline__ float bf2f(unsigned short u) {
  return __builtin_bit_cast(float, ((unsigned int)u) << 16);
}

// bijective XCD-chunk swizzle (m204 form): consecutive output wg on same XCD
__device__ __forceinline__ int xcd_swz(int orig, int nwg) {
  int q = nwg >> 3, r = nwg & 7;
  int x = orig & 7, idx = orig >> 3;
  return (x < r) ? (x * (q + 1) + idx) : (r * (q + 1) + (x - r) * q + idx);
}

// ================= stage 1: prep (build | cvt | wt_p | wt_f | wrow | vb) =================
__global__ __launch_bounds__(256) void k_prep(
    const float* __restrict__ h, const float* __restrict__ Wf,
    const float* __restrict__ Wp, const float* __restrict__ bp,
    const int* __restrict__ src, const int* __restrict__ dst,
    int* __restrict__ deg, int* __restrict__ ssrc,
    unsigned short* __restrict__ xb,
    unsigned short* __restrict__ Wtp, unsigned short* __restrict__ Wtf,
    unsigned short* __restrict__ Wpb,
    float* __restrict__ v, float* __restrict__ bb) {
  __shared__ float red[256];
  int b = blockIdx.x;
  int tid = threadIdx.x;
  if (b < 2500) {                       // ---- build ----
    int e = b * 256 + tid;
    if (e < NEDGE) {
      int d = dst[e];
      int pos = atomicAdd(&deg[d], 1);
      ssrc[d * CAP + pos] = src[e];
    }
  } else if (b < 3750) {                // ---- cvt h -> xb[:,0:128] ----
    int idx = (b - 2500) * 256 + tid;
    int n = idx >> 4, seg = idx & 15;
    const float4* hp = (const float4*)(h + n * DD + seg * 8);
    float4 x0 = hp[0], x1 = hp[1];
    ushort8 o;
    o[0] = f2bf(x0.x); o[1] = f2bf(x0.y); o[2] = f2bf(x0.z); o[3] = f2bf(x0.w);
    o[4] = f2bf(x1.x); o[5] = f2bf(x1.y); o[6] = f2bf(x1.z); o[7] = f2bf(x1.w);
    *(ushort8*)(xb + n * KK2 + seg * 8) = o;
  } else if (b < 4006) {                // ---- Wp -> Wtp (col-major bf16) ----
    int wid = tid >> 6, lane = tid & 63;
    int col = (b - 3750) * 4 + wid;
    #pragma unroll
    for (int i = 0; i < 4; ++i) {
      int kk = i * 64 + lane;
      float val = (col < NAC) ? Wp[kk * NAC + col] : 0.f;
      Wtp[col * KK2 + kk] = f2bf(val);
    }
  } else if (b < 4038) {                // ---- Wf -> Wtf (col-major bf16) ----
    int wid = tid >> 6, lane = tid & 63;
    int col = (b - 4006) * 4 + wid;
    #pragma unroll
    for (int i = 0; i < 4; ++i) {
      int kk = i * 64 + lane;
      Wtf[col * KK2 + kk] = f2bf(Wf[kk * DD + col]);
    }
  } else if (b < 4166) {                // ---- Wp -> Wpb (row-major bf16, padded) ----
    int idx = (b - 4038) * 256 + tid;
    int rrow = idx >> 7;
    int seg = idx & 127;
    ushort8 o;
    #pragma unroll
    for (int i = 0; i < 8; ++i) {
      int cc = seg * 8 + i;
      o[i] = (cc < NAC) ? f2bf(Wp[rrow * NAC + cc]) : (unsigned short)0;
    }
    *(ushort8*)(Wpb + rrow * NACP + seg * 8) = o;
  } else {                              // ---- v = Wp@bp, bb = ||bp||^2 ----
    int i = b - 4166;
    float acc = 0.f;
    for (int k = tid; k < NAC; k += 256) acc += Wp[i * NAC + k] * bp[k];
    red[tid] = acc;
    __syncthreads();
    for (int st = 128; st > 0; st >>= 1) {
      if (tid < st) red[tid] += red[tid + st];
      __syncthreads();
    }
    if (tid == 0) v[i] = red[0];
    if (i == 0) {
      __syncthreads();
      float a2 = 0.f;
      for (int k = tid; k < NAC; k += 256) { float t = bp[k]; a2 += t * t; }
      red[tid] = a2;
      __syncthreads();
      for (int st = 128; st > 0; st >>= 1) {
        if (tid < st) red[tid] += red[tid + st];
        __syncthreads();
      }
      if (tid == 0) *bb = red[0];
    }
  }
}

// ================= stage 2: gram2 (16 blocks) | aggregate (1250, MLP gather) =================
__global__ __launch_bounds__(256) void k_mid(
    const unsigned short* __restrict__ Wpb, unsigned short* __restrict__ Gb,
    const int* __restrict__ deg, const int* __restrict__ ssrc,
    unsigned short* __restrict__ xb) {
  int b = blockIdx.x;
  int tid = threadIdx.x;
  if (b < 16) {                         // ---- G = Wp@Wp^T (256x256, K=1024) ----
    int i0 = (b & 3) * 64, j0 = (b >> 2) * 64;
    int wid = tid >> 6, lane = tid & 63;
    int lr = lane & 15, lg = lane >> 4;
    f32x4 acc[4] = {};
    for (int kt = 0; kt < 32; ++kt) {
      bfrag a[4], bfr;
      #pragma unroll
      for (int m = 0; m < 4; ++m)
        a[m] = *reinterpret_cast<const bfrag*>(Wpb + (size_t)(i0 + m * 16 + lr) * NACP + kt * 32 + lg * 8);
      bfr = *reinterpret_cast<const bfrag*>(Wpb + (size_t)(j0 + wid * 16 + lr) * NACP + kt * 32 + lg * 8);
      #pragma unroll
      for (int m = 0; m < 4; ++m)
        acc[m] = __builtin_amdgcn_mfma_f32_16x16x32_bf16(a[m], bfr, acc[m], 0, 0, 0);
    }
    #pragma unroll
    for (int m = 0; m < 4; ++m)
      #pragma unroll
      for (int r = 0; r < 4; ++r) {
        int row = i0 + m * 16 + lg * 4 + r;
        int col = j0 + wid * 16 + lr;
        Gb[row * 256 + col] = f2bf(acc[m][r]);
      }
  } else {                              // ---- mean aggregate: xb[:,128:256] ----
    int wg = xcd_swz(b - 16, 1250);
    int node = wg * 16 + (tid >> 4);
    int lane = tid & 15;                // 16 lanes x 8 bf16 = 128 cols
    int dg = deg[node];
    const int* sl = ssrc + node * CAP;
    // prefetch ALL 32 candidate indices (CAP=96 >= 32: always in-bounds)
    int4 I[8];
    #pragma unroll
    for (int t = 0; t < 8; ++t) I[t] = ((const int4*)sl)[t];
    // issue 32 clamped gathers (dummy row NN is zeroed)
    ushort8 vals[32];
    #pragma unroll
    for (int t = 0; t < 8; ++t) {
      int ia[4] = {I[t].x, I[t].y, I[t].z, I[t].w};
      #pragma unroll
      for (int k = 0; k < 4; ++k) {
        int ic = (t * 4 + k < dg) ? ia[k] : NN;
        vals[t * 4 + k] = *(const ushort8*)(xb + (size_t)ic * KK2 + lane * 8);
      }
    }
    float a[8] = {};
    #pragma unroll
    for (int jj = 0; jj < 32; ++jj)
      #pragma unroll
      for (int i = 0; i < 8; ++i) a[i] += bf2f(vals[jj][i]);
    for (int j = 32; j < dg; ++j) {     // rare tail (dg>32)
      ushort8 vv = *(const ushort8*)(xb + (size_t)sl[j] * KK2 + lane * 8);
      #pragma unroll
      for (int i = 0; i < 8; ++i) a[i] += bf2f(vv[i]);
    }
    float inv = 1.f / (float)max(dg, 1);
    ushort8 o;
    #pragma unroll
    for (int i = 0; i < 8; ++i) o[i] = f2bf(a[i] * inv);
    *(ushort8*)(xb + node * KK2 + DD + lane * 8) = o;
  }
}

// ================= stage 3: fused norm(Gram) + window logits + softmax + feat =================
__global__ __launch_bounds__(256) void k_fused(
    const unsigned short* __restrict__ xb, const unsigned short* __restrict__ Gb,
    const unsigned short* __restrict__ Wtp, const unsigned short* __restrict__ Wtf,
    const float* __restrict__ bp, const float* __restrict__ bfeat,
    const float* __restrict__ v, const float* __restrict__ bbp,
    unsigned short* __restrict__ featb, _Float16* __restrict__ p_pad) {
  __shared__ int4 xs4[1024];        // 32 rows x 32 slots (bf16x8), XOR-swizzled
  __shared__ float zbuf[32][52];
  __shared__ float nrm_lds[32];
  __shared__ float nrmf_lds[32];
  int n0 = blockIdx.x * 32;
  int tid = threadIdx.x;
  for (int i = tid; i < 1024; i += 256) {
    int row = i >> 5;
    xs4[i ^ (row & 7)] = ((const int4*)xb)[(size_t)(n0 + row) * 32 + (i & 31)];
  }
  if (tid < 32) { nrm_lds[tid] = 0.f; nrmf_lds[tid] = 0.f; }
  __syncthreads();

  int wid = tid >> 6, lane = tid & 63;
  int lr = lane & 15, lg = lane >> 4;
  const unsigned short* xsu = (const unsigned short*)xs4;

  // ---- Phase Y: y = x @ G, cols wid*64..+64; norm2 partial epilogue ----
  {
    f32x4 accy[2][4] = {};
    #pragma unroll
    for (int kt = 0; kt < 8; ++kt) {
      bfrag a[2], bfr[4];
      #pragma unroll
      for (int m = 0; m < 2; ++m) {
        int slot = (m * 16 + lr) * 32 + kt * 4 + lg;
        a[m] = *reinterpret_cast<const bfrag*>(&xs4[slot ^ ((slot >> 5) & 7)]);
      }
      #pragma unroll
      for (int c = 0; c < 4; ++c) {
        int j = wid * 64 + c * 16 + lr;
        bfr[c] = *reinterpret_cast<const bfrag*>(Gb + (size_t)j * KK2 + kt * 32 + lg * 8);
      }
      #pragma unroll
      for (int m = 0; m < 2; ++m)
        #pragma unroll
        for (int c = 0; c < 4; ++c)
          accy[m][c] = __builtin_amdgcn_mfma_f32_16x16x32_bf16(a[m], bfr[c], accy[m][c], 0, 0, 0);
    }
    float vv[4];
    #pragma unroll
    for (int c = 0; c < 4; ++c) vv[c] = v[wid * 64 + c * 16 + lr];
    #pragma unroll
    for (int m = 0; m < 2; ++m)
      #pragma unroll
      for (int r = 0; r < 4; ++r) {
        int row = m * 16 + lg * 4 + r;
        float part = 0.f;
        #pragma unroll
        for (int c = 0; c < 4; ++c) {
          int k = wid * 64 + c * 16 + lr;
          int slot = row * 32 + (k >> 3);
          float xv = bf2f(xsu[(size_t)(slot ^ (row & 7)) * 8 + (k & 7)]);
          part += (accy[m][c][r] + 2.f * vv[c]) * xv;
        }
        part += __shfl_xor(part, 1); part += __shfl_xor(part, 2);
        part += __shfl_xor(part, 4); part += __shfl_xor(part, 8);
        if (lr == 0) atomicAdd(&nrm_lds[row], part);
      }
  }

  // ---- Phase W: in-graph window logits (handles graph-straddling tiles) ----
  {
    int g0 = n0 / NPG;
    int g1 = (n0 + 31) / NPG;
    for (int gp = g0; gp <= g1; ++gp) {
      int wb = gp * KPC;
      f32x4 accw[2] = {};
      #pragma unroll
      for (int kt = 0; kt < 8; ++kt) {
        bfrag a[2], bfr;
        #pragma unroll
        for (int m = 0; m < 2; ++m) {
          int slot = (m * 16 + lr) * 32 + kt * 4 + lg;
          a[m] = *reinterpret_cast<const bfrag*>(&xs4[slot ^ ((slot >> 5) & 7)]);
        }
        bfr = *reinterpret_cast<const bfrag*>(Wtp + (size_t)(wb + wid * 16 + lr) * KK2 + kt * 32 + lg * 8);
        #pragma unroll
        for (int m = 0; m < 2; ++m)
          accw[m] = __builtin_amdgcn_mfma_f32_16x16x32_bf16(a[m], bfr, accw[m], 0, 0, 0);
      }
      int wc = wid * 16 + lr;
      float bias = (wc < KPC) ? bp[wb + wc] : 0.f;
      #pragma unroll
      for (int m = 0; m < 2; ++m)
        #pragma unroll
        for (int r = 0; r < 4; ++r) {
          int row = m * 16 + lg * 4 + r;
          if (wc < KPC && (n0 + row) / NPG == gp)
            zbuf[row][wc] = accw[m][r] + bias;
        }
    }
  }

  // ---- Phase F: feat GEMM, cols wid*32..+32 ----
  f32x4 accf[2][2] = {};
  {
    #pragma unroll
    for (int kt = 0; kt < 8; ++kt) {
      bfrag a[2], bfr[2];
      #pragma unroll
      for (int m = 0; m < 2; ++m) {
        int slot = (m * 16 + lr) * 32 + kt * 4 + lg;
        a[m] = *reinterpret_cast<const bfrag*>(&xs4[slot ^ ((slot >> 5) & 7)]);
      }
      #pragma unroll
      for (int c = 0; c < 2; ++c) {
        int col = wid * 32 + c * 16 + lr;
        bfr[c] = *reinterpret_cast<const bfrag*>(Wtf + (size_t)col * KK2 + kt * 32 + lg * 8);
      }
      #pragma unroll
      for (int m = 0; m < 2; ++m)
        #pragma unroll
        for (int c = 0; c < 2; ++c)
          accf[m][c] = __builtin_amdgcn_mfma_f32_16x16x32_bf16(a[m], bfr[c], accf[m][c], 0, 0, 0);
    }
    float nf[2][4] = {};
    #pragma unroll
    for (int c = 0; c < 2; ++c) {
      int col = wid * 32 + c * 16 + lr;
      float bias = bfeat[col];
      #pragma unroll
      for (int m = 0; m < 2; ++m)
        #pragma unroll
        for (int r = 0; r < 4; ++r) {
          float z = accf[m][c][r] + bias;
          accf[m][c][r] = z;
          nf[m][r] += z * z;
        }
    }
    #pragma unroll
    for (int m = 0; m < 2; ++m)
      #pragma unroll
      for (int r = 0; r < 4; ++r) {
        float p = nf[m][r];
        p += __shfl_xor(p, 1); p += __shfl_xor(p, 2);
        p += __shfl_xor(p, 4); p += __shfl_xor(p, 8);
        if (lr == 0) atomicAdd(&nrmf_lds[m * 16 + lg * 4 + r], p);
      }
  }
  __syncthreads();

  // feat write (bf16)
  #pragma unroll
  for (int m = 0; m < 2; ++m)
    #pragma unroll
    for (int r = 0; r < 4; ++r) {
      int row = m * 16 + lg * 4 + r;
      float sc = 1.f / fmaxf(sqrtf(nrmf_lds[row]), 1e-12f);
      #pragma unroll
      for (int c = 0; c < 2; ++c) {
        int col = wid * 32 + c * 16 + lr;
        featb[(size_t)(n0 + row) * DD + col] = f2bf(fmaxf(accf[m][c][r] * sc, 0.f));
      }
    }

  // softmax: 4 threads per node -> p_pad fp16
  if (tid < 128) {
    int node = tid >> 2, q = tid & 3;
    float nv = nrm_lds[node] + bbp[0];
    float inv = 1.f / fmaxf(sqrtf(fmaxf(nv, 0.f)), 1e-12f);
    float e[16];
    float mx = -1e30f;
    #pragma unroll
    for (int i = 0; i < 16; ++i) {
      int cc = q * 16 + i;
      float sv = (cc < KPC) ? fmaxf(zbuf[node][cc] * inv, 0.f) : -1e30f;
      e[i] = sv;
      mx = fmaxf(mx, sv);
    }
    mx = fmaxf(mx, __shfl_xor(mx, 1));
    mx = fmaxf(mx, __shfl_xor(mx, 2));
    float esum = 0.f;
    #pragma unroll
    for (int i = 0; i < 16; ++i) {
      int cc = q * 16 + i;
      float ev = (cc < KPC) ? __expf(e[i] - mx) : 0.f;
      e[i] = ev;
      esum += ev;
    }
    esum += __shfl_xor(esum, 1);
    esum += __shfl_xor(esum, 2);
    float isum = 1.f / esum;
    half8 o0, o1;
    #pragma unroll
    for (int i = 0; i < 8; ++i) {
      o0[i] = (_Float16)(e[i] * isum);
      o1[i] = (_Float16)(e[i + 8] * isum);
    }
    *(half8*)&p_pad[(size_t)(n0 + node) * KPAD + q * 16] = o0;
    *(half8*)&p_pad[(size_t)(n0 + node) * KPAD + q * 16 + 8] = o1;
  }
}

// ================= stage 4: a_s gather (625, MLP) | hpool (400) =================
__global__ __launch_bounds__(256) void k_asp(
    const _Float16* __restrict__ p_pad, const int* __restrict__ deg,
    const int* __restrict__ ssrc, float* __restrict__ asum_pad,
    const unsigned short* __restrict__ featb, float* __restrict__ out) {
  __shared__ float pl[50][52];
  int b = blockIdx.x;
  int tid = threadIdx.x;
  if (b < 625) {                        // ---- a_s[n] = sum p_pad[src] (fp16 MLP gather) ----
    int wg = xcd_swz(b, 625);
    int n = wg * 32 + (tid >> 3);
    int lane = tid & 7;                 // 8 lanes x 8 fp16 = 64 cols
    int dg = deg[n];
    const int* sl = ssrc + n * CAP;
    int4 I[8];
    #pragma unroll
    for (int t = 0; t < 8; ++t) I[t] = ((const int4*)sl)[t];
    half8 vals[32];
    #pragma unroll
    for (int t = 0; t < 8; ++t) {
      int ia[4] = {I[t].x, I[t].y, I[t].z, I[t].w};
      #pragma unroll
      for (int k = 0; k < 4; ++k) {
        int ic = (t * 4 + k < dg) ? ia[k] : NN;   // dummy row NN zeroed
        vals[t * 4 + k] = *(const half8*)(p_pad + (size_t)ic * KPAD + lane * 8);
      }
    }
    float a[8] = {};
    #pragma unroll
    for (int jj = 0; jj < 32; ++jj)
      #pragma unroll
      for (int i = 0; i < 8; ++i) a[i] += (float)vals[jj][i];
    for (int j = 32; j < dg; ++j) {     // rare tail
      half8 vv = *(const half8*)(p_pad + (size_t)sl[j] * KPAD + lane * 8);
      #pragma unroll
      for (int i = 0; i < 8; ++i) a[i] += (float)vv[i];
    }
    float* dstp = asum_pad + (size_t)n * KPAD + lane * 8;
    *(float4*)dstp = make_float4(a[0], a[1], a[2], a[3]);
    *(float4*)(dstp + 4) = make_float4(a[4], a[5], a[6], a[7]);
  } else {                              // ---- h_pool += p^T feat ----
    int q = b - 625;
    int g = q / 20, ch = q % 20;
    const int CH = 50;
    int nbase = g * NPG + ch * CH;
    for (int l = tid; l < CH * KPC; l += 256) {
      int r = l / KPC, kk = l % KPC;
      pl[r][kk] = (float)p_pad[(size_t)(nbase + r) * KPAD + kk];
    }
    __syncthreads();
    int d2 = tid & 63;                  // column pair 2*d2, 2*d2+1
    int kq = tid >> 6;
    int kstart = kq * 13;
    int kcount = min(13, KPC - kstart); // 13,13,13,11
    float acc0[13] = {};
    float acc1[13] = {};
    for (int r = 0; r < CH; ++r) {
      unsigned int u = *(const unsigned int*)(featb + (size_t)(nbase + r) * DD + 2 * d2);
      float f0 = bf2f((unsigned short)(u & 0xffff));
      float f1 = bf2f((unsigned short)(u >> 16));
      #pragma unroll
      for (int i = 0; i < 13; ++i) {
        if (i < kcount) {
          float pv = pl[r][kstart + i];
          acc0[i] += pv * f0;
          acc1[i] += pv * f1;
        }
      }
    }
    for (int i = 0; i < kcount; ++i) {
      int k = kstart + i;
      atomicAdd(&out[1000000 + (g * KPC + k) * DD + 2 * d2], acc0[i]);
      atomicAdd(&out[1000000 + (g * KPC + k) * DD + 2 * d2 + 1], acc1[i]);
    }
  }
}

// ================= stage 5: adj block: out[(g*50+k1)*1000 + g*50+k2] += p^T a_s =================
__global__ __launch_bounds__(256) void k_adj(
    const _Float16* __restrict__ p_pad, const float* __restrict__ asum_pad,
    float* __restrict__ out) {
  const int CH = 50;
  int g = blockIdx.x / 20, ch = blockIdx.x % 20;
  __shared__ float pl[CH][52];
  int nbase = g * NPG + ch * CH;
  for (int l = threadIdx.x; l < CH * KPC; l += 256) {
    int r = l / KPC, kk = l % KPC;
    pl[r][kk] = (float)p_pad[(size_t)(nbase + r) * KPAD + kk];
  }
  __syncthreads();
  int k2 = threadIdx.x & 63;
  int wq = threadIdx.x >> 6;
  int kstart = wq * 13;
  int kcount = min(13, KPC - kstart);
  if (k2 < KPC) {
    float acc[13] = {};
    for (int r = 0; r < CH; ++r) {
      float av = asum_pad[(size_t)(nbase + r) * KPAD + k2];
      #pragma unroll
      for (int i = 0; i < 13; ++i) {
        if (i < kcount) acc[i] += pl[r][kstart + i] * av;
      }
    }
    for (int i = 0; i < kcount; ++i) {
      atomicAdd(&out[(g * KPC + kstart + i) * NAC + g * KPC + k2], acc[i]);
    }
  }
}

extern "C" void kernel_launch(void* const* d_in, const int* in_sizes, int n_in,
                              void* d_out, int out_size, void* d_ws, size_t ws_size,
                              hipStream_t stream) {
  const float* h = (const float*)d_in[0];
  const float* Wf = (const float*)d_in[1];
  const float* bf = (const float*)d_in[2];
  const float* Wp = (const float*)d_in[3];
  const float* bp = (const float*)d_in[4];
  const int* src = (const int*)d_in[5];
  const int* dst = (const int*)d_in[6];
  // d_in[7] (mask) unused: block-diagonal by construction.
  float* out = (float*)d_out;
  char* ws = (char*)d_ws;

  int* deg = (int*)(ws + 0);                                // 80 KB
  int* ssrc = (int*)(ws + 80000);                           // 7.68 MB -> 7,760,000
  unsigned short* xb = (unsigned short*)(ws + 7760000);     // 20001 x 512B = 10,240,512
  unsigned short* featb = (unsigned short*)(ws + 18004096); // 5.12 MB (bf16)
  _Float16* p_pad = (_Float16*)(ws + 23124992);             // 20001 x 128B = 2,560,128
  float* asum_pad = (float*)(ws + 25690112);                // 5.12 MB
  unsigned short* Wpb = (unsigned short*)(ws + 30810112);   // 512 KB
  unsigned short* Gb = (unsigned short*)(ws + 31334400);    // 128 KB
  float* v = (float*)(ws + 31465472);                       // 1 KB
  float* bb = (float*)(ws + 31466496);                      // 4 B
  unsigned short* Wtp = (unsigned short*)(ws + 31467520);   // 512 KB
  unsigned short* Wtf = (unsigned short*)(ws + 31991808);   // 64 KB

  hipMemsetAsync(deg, 0, 80000, stream);
  hipMemsetAsync((char*)xb + (size_t)NN * KK2 * 2, 0, 512, stream);     // dummy row NN
  hipMemsetAsync((char*)p_pad + (size_t)NN * KPAD * 2, 0, 128, stream); // dummy row NN
  hipMemsetAsync(d_out, 0, (size_t)out_size * sizeof(float), stream);

  k_prep<<<4422, 256, 0, stream>>>(h, Wf, Wp, bp, src, dst, deg, ssrc, xb, Wtp, Wtf, Wpb, v, bb);
  k_mid<<<1266, 256, 0, stream>>>(Wpb, Gb, deg, ssrc, xb);
  k_fused<<<625, 256, 0, stream>>>(xb, Gb, Wtp, Wtf, bp, bf, v, bb, featb, p_pad);
  k_asp<<<1025, 256, 0, stream>>>(p_pad, deg, ssrc, asum_pad, featb, out);
  k_adj<<<400, 256, 0, stream>>>(p_pad, asum_pad, out);
}

// Round 7
// 151.577 us; speedup vs baseline: 1.3032x; 1.3032x over previous
//
#include <hip/hip_runtime.h>

#define NN 20000      // nodes
#define NPG 1000      // nodes per graph
#define NBG 20        // graphs
#define DD 128        // feature dim
#define KK2 256       // concat dim
#define KPC 50        // clusters per graph
#define KPAD 64       // padded cluster cols
#define NAC 1000      // total clusters
#define NACP 1024     // padded cluster cols
#define NPGP 1024     // padded nodes per graph (K dim of final GEMMs)
#define NEDGE 640000
#define CAP 96        // bucket capacity per node (mean deg 32, +11 sigma)

typedef __attribute__((ext_vector_type(8))) short bfrag;      // 8 bf16
typedef __attribute__((ext_vector_type(4))) float f32x4;
typedef __attribute__((ext_vector_type(8))) unsigned short ushort8;
typedef __attribute__((ext_vector_type(8))) _Float16 half8;

__device__ __forceinline__ float4 f4add(float4 a, float4 b) {
  return make_float4(a.x + b.x, a.y + b.y, a.z + b.z, a.w + b.w);
}

__device__ __forceinline__ unsigned short f2bf(float f) {
  unsigned int u = __builtin_bit_cast(unsigned int, f);
  unsigned int r = (u + 0x7FFFu + ((u >> 16) & 1u)) >> 16;   // RNE
  return (unsigned short)r;
}
__device__ __forceinline__ float bf2f(unsigned short u) {
  return __builtin_bit_cast(float, ((unsigned int)u) << 16);
}

// bijective XCD-chunk swizzle (m204 form)
__device__ __forceinline__ int xcd_swz(int orig, int nwg) {
  int q = nwg >> 3, r = nwg & 7;
  int x = orig & 7, idx = orig >> 3;
  return (x < r) ? (x * (q + 1) + idx) : (r * (q + 1) + (x - r) * q + idx);
}

// ================= stage 1: prep (build | cvt | wt_p | wt_f | wrow | vb) =================
__global__ __launch_bounds__(256) void k_prep(
    const float* __restrict__ h, const float* __restrict__ Wf,
    const float* __restrict__ Wp, const float* __restrict__ bp,
    const int* __restrict__ src, const int* __restrict__ dst,
    int* __restrict__ deg, int* __restrict__ ssrc,
    unsigned short* __restrict__ xb,
    unsigned short* __restrict__ Wtp, unsigned short* __restrict__ Wtf,
    unsigned short* __restrict__ Wpb,
    float* __restrict__ v, float* __restrict__ bb) {
  __shared__ float red[256];
  int b = blockIdx.x;
  int tid = threadIdx.x;
  if (b < 2500) {                       // ---- build ----
    int e = b * 256 + tid;
    if (e < NEDGE) {
      int d = dst[e];
      int pos = atomicAdd(&deg[d], 1);
      ssrc[d * CAP + pos] = src[e];
    }
  } else if (b < 3750) {                // ---- cvt h -> xb[:,0:128] ----
    int idx = (b - 2500) * 256 + tid;
    int n = idx >> 4, seg = idx & 15;
    const float4* hp = (const float4*)(h + n * DD + seg * 8);
    float4 x0 = hp[0], x1 = hp[1];
    ushort8 o;
    o[0] = f2bf(x0.x); o[1] = f2bf(x0.y); o[2] = f2bf(x0.z); o[3] = f2bf(x0.w);
    o[4] = f2bf(x1.x); o[5] = f2bf(x1.y); o[6] = f2bf(x1.z); o[7] = f2bf(x1.w);
    *(ushort8*)(xb + n * KK2 + seg * 8) = o;
  } else if (b < 4006) {                // ---- Wp -> Wtp (col-major bf16) ----
    int wid = tid >> 6, lane = tid & 63;
    int col = (b - 3750) * 4 + wid;
    #pragma unroll
    for (int i = 0; i < 4; ++i) {
      int kk = i * 64 + lane;
      float val = (col < NAC) ? Wp[kk * NAC + col] : 0.f;
      Wtp[col * KK2 + kk] = f2bf(val);
    }
  } else if (b < 4038) {                // ---- Wf -> Wtf (col-major bf16) ----
    int wid = tid >> 6, lane = tid & 63;
    int col = (b - 4006) * 4 + wid;
    #pragma unroll
    for (int i = 0; i < 4; ++i) {
      int kk = i * 64 + lane;
      Wtf[col * KK2 + kk] = f2bf(Wf[kk * DD + col]);
    }
  } else if (b < 4166) {                // ---- Wp -> Wpb (row-major bf16, padded) ----
    int idx = (b - 4038) * 256 + tid;
    int rrow = idx >> 7;
    int seg = idx & 127;
    ushort8 o;
    #pragma unroll
    for (int i = 0; i < 8; ++i) {
      int cc = seg * 8 + i;
      o[i] = (cc < NAC) ? f2bf(Wp[rrow * NAC + cc]) : (unsigned short)0;
    }
    *(ushort8*)(Wpb + rrow * NACP + seg * 8) = o;
  } else {                              // ---- v = Wp@bp, bb = ||bp||^2 ----
    int i = b - 4166;
    float acc = 0.f;
    for (int k = tid; k < NAC; k += 256) acc += Wp[i * NAC + k] * bp[k];
    red[tid] = acc;
    __syncthreads();
    for (int st = 128; st > 0; st >>= 1) {
      if (tid < st) red[tid] += red[tid + st];
      __syncthreads();
    }
    if (tid == 0) v[i] = red[0];
    if (i == 0) {
      __syncthreads();
      float a2 = 0.f;
      for (int k = tid; k < NAC; k += 256) { float t = bp[k]; a2 += t * t; }
      red[tid] = a2;
      __syncthreads();
      for (int st = 128; st > 0; st >>= 1) {
        if (tid < st) red[tid] += red[tid + st];
        __syncthreads();
      }
      if (tid == 0) *bb = red[0];
    }
  }
}

// ================= stage 2: gram2 (16 blocks) | aggregate (1250, rolling gather) =================
__global__ __launch_bounds__(256) void k_mid(
    const unsigned short* __restrict__ Wpb, unsigned short* __restrict__ Gb,
    const int* __restrict__ deg, const int* __restrict__ ssrc,
    unsigned short* __restrict__ xb) {
  int b = blockIdx.x;
  int tid = threadIdx.x;
  if (b < 16) {                         // ---- G = Wp@Wp^T (256x256, K=1024) ----
    int i0 = (b & 3) * 64, j0 = (b >> 2) * 64;
    int wid = tid >> 6, lane = tid & 63;
    int lr = lane & 15, lg = lane >> 4;
    f32x4 acc[4] = {};
    for (int kt = 0; kt < 32; ++kt) {
      bfrag a[4], bfr;
      #pragma unroll
      for (int m = 0; m < 4; ++m)
        a[m] = *reinterpret_cast<const bfrag*>(Wpb + (size_t)(i0 + m * 16 + lr) * NACP + kt * 32 + lg * 8);
      bfr = *reinterpret_cast<const bfrag*>(Wpb + (size_t)(j0 + wid * 16 + lr) * NACP + kt * 32 + lg * 8);
      #pragma unroll
      for (int m = 0; m < 4; ++m)
        acc[m] = __builtin_amdgcn_mfma_f32_16x16x32_bf16(a[m], bfr, acc[m], 0, 0, 0);
    }
    #pragma unroll
    for (int m = 0; m < 4; ++m)
      #pragma unroll
      for (int r = 0; r < 4; ++r) {
        int row = i0 + m * 16 + lg * 4 + r;
        int col = j0 + wid * 16 + lr;
        Gb[row * 256 + col] = f2bf(acc[m][r]);
      }
  } else {                              // ---- mean aggregate: xb[:,128:256] ----
    int wg = xcd_swz(b - 16, 1250);
    int node = wg * 16 + (tid >> 4);
    int lane = tid & 15;                // 16 lanes x 8 bf16 = 128 cols
    int dg = deg[node];
    const int* sl = ssrc + node * CAP;
    float a[8] = {};
    int j = 0;
    for (; j + 4 <= dg; j += 4) {
      int4 idx = *(const int4*)&sl[j];
      ushort8 v0 = *(const ushort8*)(xb + (size_t)idx.x * KK2 + lane * 8);
      ushort8 v1 = *(const ushort8*)(xb + (size_t)idx.y * KK2 + lane * 8);
      ushort8 v2 = *(const ushort8*)(xb + (size_t)idx.z * KK2 + lane * 8);
      ushort8 v3 = *(const ushort8*)(xb + (size_t)idx.w * KK2 + lane * 8);
      #pragma unroll
      for (int i = 0; i < 8; ++i)
        a[i] += bf2f(v0[i]) + bf2f(v1[i]) + bf2f(v2[i]) + bf2f(v3[i]);
    }
    for (; j < dg; ++j) {
      ushort8 vv = *(const ushort8*)(xb + (size_t)sl[j] * KK2 + lane * 8);
      #pragma unroll
      for (int i = 0; i < 8; ++i) a[i] += bf2f(vv[i]);
    }
    float inv = 1.f / (float)max(dg, 1);
    ushort8 o;
    #pragma unroll
    for (int i = 0; i < 8; ++i) o[i] = f2bf(a[i] * inv);
    *(ushort8*)(xb + node * KK2 + DD + lane * 8) = o;
  }
}

// ================= stage 3: fused norm(Gram) + window logits + softmax + feat =================
__global__ __launch_bounds__(256) void k_fused(
    const unsigned short* __restrict__ xb, const unsigned short* __restrict__ Gb,
    const unsigned short* __restrict__ Wtp, const unsigned short* __restrict__ Wtf,
    const float* __restrict__ bp, const float* __restrict__ bfeat,
    const float* __restrict__ v, const float* __restrict__ bbp,
    unsigned short* __restrict__ featb, _Float16* __restrict__ p_pad,
    unsigned short* __restrict__ pT) {
  __shared__ int4 xs4[1024];        // 32 rows x 32 slots (bf16x8), XOR-swizzled
  __shared__ float zbuf[32][52];
  __shared__ float nrm_lds[32];
  __shared__ float nrmf_lds[32];
  int n0 = blockIdx.x * 32;
  int tid = threadIdx.x;
  for (int i = tid; i < 1024; i += 256) {
    int row = i >> 5;
    xs4[i ^ (row & 7)] = ((const int4*)xb)[(size_t)(n0 + row) * 32 + (i & 31)];
  }
  if (tid < 32) { nrm_lds[tid] = 0.f; nrmf_lds[tid] = 0.f; }
  __syncthreads();

  int wid = tid >> 6, lane = tid & 63;
  int lr = lane & 15, lg = lane >> 4;
  const unsigned short* xsu = (const unsigned short*)xs4;

  // ---- Phase Y: y = x @ G, cols wid*64..+64; norm2 partial epilogue ----
  {
    f32x4 accy[2][4] = {};
    #pragma unroll
    for (int kt = 0; kt < 8; ++kt) {
      bfrag a[2], bfr[4];
      #pragma unroll
      for (int m = 0; m < 2; ++m) {
        int slot = (m * 16 + lr) * 32 + kt * 4 + lg;
        a[m] = *reinterpret_cast<const bfrag*>(&xs4[slot ^ ((slot >> 5) & 7)]);
      }
      #pragma unroll
      for (int c = 0; c < 4; ++c) {
        int j = wid * 64 + c * 16 + lr;
        bfr[c] = *reinterpret_cast<const bfrag*>(Gb + (size_t)j * KK2 + kt * 32 + lg * 8);
      }
      #pragma unroll
      for (int m = 0; m < 2; ++m)
        #pragma unroll
        for (int c = 0; c < 4; ++c)
          accy[m][c] = __builtin_amdgcn_mfma_f32_16x16x32_bf16(a[m], bfr[c], accy[m][c], 0, 0, 0);
    }
    float vv[4];
    #pragma unroll
    for (int c = 0; c < 4; ++c) vv[c] = v[wid * 64 + c * 16 + lr];
    #pragma unroll
    for (int m = 0; m < 2; ++m)
      #pragma unroll
      for (int r = 0; r < 4; ++r) {
        int row = m * 16 + lg * 4 + r;
        float part = 0.f;
        #pragma unroll
        for (int c = 0; c < 4; ++c) {
          int k = wid * 64 + c * 16 + lr;
          int slot = row * 32 + (k >> 3);
          float xv = bf2f(xsu[(size_t)(slot ^ (row & 7)) * 8 + (k & 7)]);
          part += (accy[m][c][r] + 2.f * vv[c]) * xv;
        }
        part += __shfl_xor(part, 1); part += __shfl_xor(part, 2);
        part += __shfl_xor(part, 4); part += __shfl_xor(part, 8);
        if (lr == 0) atomicAdd(&nrm_lds[row], part);
      }
  }

  // ---- Phase W: in-graph window logits (handles graph-straddling tiles) ----
  {
    int g0 = n0 / NPG;
    int g1 = (n0 + 31) / NPG;
    for (int gp = g0; gp <= g1; ++gp) {
      int wb = gp * KPC;
      f32x4 accw[2] = {};
      #pragma unroll
      for (int kt = 0; kt < 8; ++kt) {
        bfrag a[2], bfr;
        #pragma unroll
        for (int m = 0; m < 2; ++m) {
          int slot = (m * 16 + lr) * 32 + kt * 4 + lg;
          a[m] = *reinterpret_cast<const bfrag*>(&xs4[slot ^ ((slot >> 5) & 7)]);
        }
        bfr = *reinterpret_cast<const bfrag*>(Wtp + (size_t)(wb + wid * 16 + lr) * KK2 + kt * 32 + lg * 8);
        #pragma unroll
        for (int m = 0; m < 2; ++m)
          accw[m] = __builtin_amdgcn_mfma_f32_16x16x32_bf16(a[m], bfr, accw[m], 0, 0, 0);
      }
      int wc = wid * 16 + lr;
      float bias = (wc < KPC) ? bp[wb + wc] : 0.f;
      #pragma unroll
      for (int m = 0; m < 2; ++m)
        #pragma unroll
        for (int r = 0; r < 4; ++r) {
          int row = m * 16 + lg * 4 + r;
          if (wc < KPC && (n0 + row) / NPG == gp)
            zbuf[row][wc] = accw[m][r] + bias;
        }
    }
  }

  // ---- Phase F: feat GEMM, cols wid*32..+32 ----
  f32x4 accf[2][2] = {};
  {
    #pragma unroll
    for (int kt = 0; kt < 8; ++kt) {
      bfrag a[2], bfr[2];
      #pragma unroll
      for (int m = 0; m < 2; ++m) {
        int slot = (m * 16 + lr) * 32 + kt * 4 + lg;
        a[m] = *reinterpret_cast<const bfrag*>(&xs4[slot ^ ((slot >> 5) & 7)]);
      }
      #pragma unroll
      for (int c = 0; c < 2; ++c) {
        int col = wid * 32 + c * 16 + lr;
        bfr[c] = *reinterpret_cast<const bfrag*>(Wtf + (size_t)col * KK2 + kt * 32 + lg * 8);
      }
      #pragma unroll
      for (int m = 0; m < 2; ++m)
        #pragma unroll
        for (int c = 0; c < 2; ++c)
          accf[m][c] = __builtin_amdgcn_mfma_f32_16x16x32_bf16(a[m], bfr[c], accf[m][c], 0, 0, 0);
    }
    float nf[2][4] = {};
    #pragma unroll
    for (int c = 0; c < 2; ++c) {
      int col = wid * 32 + c * 16 + lr;
      float bias = bfeat[col];
      #pragma unroll
      for (int m = 0; m < 2; ++m)
        #pragma unroll
        for (int r = 0; r < 4; ++r) {
          float z = accf[m][c][r] + bias;
          accf[m][c][r] = z;
          nf[m][r] += z * z;
        }
    }
    #pragma unroll
    for (int m = 0; m < 2; ++m)
      #pragma unroll
      for (int r = 0; r < 4; ++r) {
        float p = nf[m][r];
        p += __shfl_xor(p, 1); p += __shfl_xor(p, 2);
        p += __shfl_xor(p, 4); p += __shfl_xor(p, 8);
        if (lr == 0) atomicAdd(&nrmf_lds[m * 16 + lg * 4 + r], p);
      }
  }
  __syncthreads();

  // feat write (bf16)
  #pragma unroll
  for (int m = 0; m < 2; ++m)
    #pragma unroll
    for (int r = 0; r < 4; ++r) {
      int row = m * 16 + lg * 4 + r;
      float sc = 1.f / fmaxf(sqrtf(nrmf_lds[row]), 1e-12f);
      #pragma unroll
      for (int c = 0; c < 2; ++c) {
        int col = wid * 32 + c * 16 + lr;
        featb[(size_t)(n0 + row) * DD + col] = f2bf(fmaxf(accf[m][c][r] * sc, 0.f));
      }
    }

  // softmax: 4 threads per node -> p_pad (fp16) and pT (bf16 [g][64][1024])
  if (tid < 128) {
    int node = tid >> 2, q = tid & 3;
    float nv = nrm_lds[node] + bbp[0];
    float inv = 1.f / fmaxf(sqrtf(fmaxf(nv, 0.f)), 1e-12f);
    float e[16];
    float mx = -1e30f;
    #pragma unroll
    for (int i = 0; i < 16; ++i) {
      int cc = q * 16 + i;
      float sv = (cc < KPC) ? fmaxf(zbuf[node][cc] * inv, 0.f) : -1e30f;
      e[i] = sv;
      mx = fmaxf(mx, sv);
    }
    mx = fmaxf(mx, __shfl_xor(mx, 1));
    mx = fmaxf(mx, __shfl_xor(mx, 2));
    float esum = 0.f;
    #pragma unroll
    for (int i = 0; i < 16; ++i) {
      int cc = q * 16 + i;
      float ev = (cc < KPC) ? __expf(e[i] - mx) : 0.f;
      e[i] = ev;
      esum += ev;
    }
    esum += __shfl_xor(esum, 1);
    esum += __shfl_xor(esum, 2);
    float isum = 1.f / esum;
    int n = n0 + node;
    int gg = n / NPG;
    int nloc = n - gg * NPG;
    half8 o0, o1;
    #pragma unroll
    for (int i = 0; i < 8; ++i) {
      o0[i] = (_Float16)(e[i] * isum);
      o1[i] = (_Float16)(e[i + 8] * isum);
    }
    *(half8*)&p_pad[(size_t)n * KPAD + q * 16] = o0;
    *(half8*)&p_pad[(size_t)n * KPAD + q * 16 + 8] = o1;
    #pragma unroll
    for (int i = 0; i < 16; ++i) {
      int cc = q * 16 + i;
      pT[((size_t)gg * KPAD + cc) * NPGP + nloc] = f2bf(e[i] * isum);
    }
  }
}

// ================= stage 4: a_s gather (625, rolling) =================
__global__ __launch_bounds__(256) void k_as(
    const _Float16* __restrict__ p_pad, const int* __restrict__ deg,
    const int* __restrict__ ssrc, float* __restrict__ asum_pad) {
  int wg = xcd_swz(blockIdx.x, 625);
  int n = wg * 32 + (threadIdx.x >> 3);
  int lane = threadIdx.x & 7;           // 8 lanes x 8 fp16 = 64 cols
  int dg = deg[n];
  const int* sl = ssrc + n * CAP;
  float a[8] = {};
  int j = 0;
  for (; j + 4 <= dg; j += 4) {
    int4 idx = *(const int4*)&sl[j];
    half8 v0 = *(const half8*)(p_pad + (size_t)idx.x * KPAD + lane * 8);
    half8 v1 = *(const half8*)(p_pad + (size_t)idx.y * KPAD + lane * 8);
    half8 v2 = *(const half8*)(p_pad + (size_t)idx.z * KPAD + lane * 8);
    half8 v3 = *(const half8*)(p_pad + (size_t)idx.w * KPAD + lane * 8);
    #pragma unroll
    for (int i = 0; i < 8; ++i)
      a[i] += (float)v0[i] + (float)v1[i] + (float)v2[i] + (float)v3[i];
  }
  for (; j < dg; ++j) {
    half8 vv = *(const half8*)(p_pad + (size_t)sl[j] * KPAD + lane * 8);
    #pragma unroll
    for (int i = 0; i < 8; ++i) a[i] += (float)vv[i];
  }
  float* dstp = asum_pad + (size_t)n * KPAD + lane * 8;
  *(float4*)dstp = make_float4(a[0], a[1], a[2], a[3]);
  *(float4*)(dstp + 4) = make_float4(a[4], a[5], a[6], a[7]);
}

// ================= stage 5: per-graph GEMMs h_pool = pT@feat, adj = pT@a_s (no atomics) =================
__global__ __launch_bounds__(256) void k_final(
    const unsigned short* __restrict__ pT, const unsigned short* __restrict__ featb,
    const float* __restrict__ asum_pad, float* __restrict__ out) {
  __shared__ unsigned short ftT[128 * 72];   // [col][node], stride 72 (16B-aligned rows)
  __shared__ unsigned short asT[64 * 72];    // [k2][node]
  int g = blockIdx.x;
  int tid = threadIdx.x;
  int wid = tid >> 6, lane = tid & 63;
  int lr = lane & 15, lg = lane >> 4;
  int r = tid & 63;                     // staging node-row (lane-major: conflict-free LDS writes)
  int cq = tid >> 6;                    // staging col-quarter
  f32x4 acch[4][2] = {};                // h_pool: 4 row-frags x cols (wid*32 + c*16)
  f32x4 acca[4] = {};                   // adj: cols wid*16

  for (int t = 0; t < 16; ++t) {
    int nb = t * 64;
    int nloc = nb + r;
    // ---- stage feat tile (transposed): ftT[col][r] ----
    if (nloc < NPG) {
      const ushort8* fr = (const ushort8*)(featb + (size_t)(g * NPG + nloc) * DD + cq * 32);
      #pragma unroll
      for (int u = 0; u < 4; ++u) {
        ushort8 vv = fr[u];
        #pragma unroll
        for (int e2 = 0; e2 < 8; ++e2)
          ftT[(cq * 32 + u * 8 + e2) * 72 + r] = vv[e2];
      }
      const float4* ar = (const float4*)(asum_pad + (size_t)(g * NPG + nloc) * KPAD + cq * 16);
      #pragma unroll
      for (int u = 0; u < 4; ++u) {
        float4 av = ar[u];
        asT[(cq * 16 + u * 4 + 0) * 72 + r] = f2bf(av.x);
        asT[(cq * 16 + u * 4 + 1) * 72 + r] = f2bf(av.y);
        asT[(cq * 16 + u * 4 + 2) * 72 + r] = f2bf(av.z);
        asT[(cq * 16 + u * 4 + 3) * 72 + r] = f2bf(av.w);
      }
    } else {
      #pragma unroll
      for (int u = 0; u < 32; ++u) ftT[(cq * 32 + u) * 72 + r] = 0;
      #pragma unroll
      for (int u = 0; u < 16; ++u) asT[(cq * 16 + u) * 72 + r] = 0;
    }
    __syncthreads();
    // ---- A-frags from pT (global, contiguous; zero for pad cols) ----
    bfrag a[4][2];
    #pragma unroll
    for (int m = 0; m < 4; ++m)
      #pragma unroll
      for (int kk = 0; kk < 2; ++kk)
        a[m][kk] = *(const bfrag*)(pT + ((size_t)g * KPAD + m * 16 + lr) * NPGP + nb + kk * 32 + lg * 8);
    // ---- h_pool MFMAs ----
    #pragma unroll
    for (int c = 0; c < 2; ++c) {
      int col = wid * 32 + c * 16 + lr;
      #pragma unroll
      for (int kk = 0; kk < 2; ++kk) {
        bfrag bfv = *(const bfrag*)&ftT[col * 72 + kk * 32 + lg * 8];
        #pragma unroll
        for (int m = 0; m < 4; ++m)
          acch[m][c] = __builtin_amdgcn_mfma_f32_16x16x32_bf16(a[m][kk], bfv, acch[m][c], 0, 0, 0);
      }
    }
    // ---- adj MFMAs ----
    {
      int col2 = wid * 16 + lr;
      #pragma unroll
      for (int kk = 0; kk < 2; ++kk) {
        bfrag bfv = *(const bfrag*)&asT[col2 * 72 + kk * 32 + lg * 8];
        #pragma unroll
        for (int m = 0; m < 4; ++m)
          acca[m] = __builtin_amdgcn_mfma_f32_16x16x32_bf16(a[m][kk], bfv, acca[m], 0, 0, 0);
      }
    }
    __syncthreads();
  }
  // ---- plain stores (one writer per element) ----
  int k2 = wid * 16 + lr;
  #pragma unroll
  for (int m = 0; m < 4; ++m)
    #pragma unroll
    for (int rr = 0; rr < 4; ++rr) {
      int i = m * 16 + lg * 4 + rr;
      if (i < KPC) {
        #pragma unroll
        for (int c = 0; c < 2; ++c) {
          int col = wid * 32 + c * 16 + lr;
          out[1000000 + (size_t)(g * KPC + i) * DD + col] = acch[m][c][rr];
        }
        if (k2 < KPC)
          out[(size_t)(g * KPC + i) * NAC + g * KPC + k2] = acca[m][rr];
      }
    }
}

extern "C" void kernel_launch(void* const* d_in, const int* in_sizes, int n_in,
                              void* d_out, int out_size, void* d_ws, size_t ws_size,
                              hipStream_t stream) {
  const float* h = (const float*)d_in[0];
  const float* Wf = (const float*)d_in[1];
  const float* bf = (const float*)d_in[2];
  const float* Wp = (const float*)d_in[3];
  const float* bp = (const float*)d_in[4];
  const int* src = (const int*)d_in[5];
  const int* dst = (const int*)d_in[6];
  // d_in[7] (mask) unused: block-diagonal by construction.
  float* out = (float*)d_out;
  char* ws = (char*)d_ws;

  int* deg = (int*)(ws + 0);                                // 80 KB
  int* ssrc = (int*)(ws + 80000);                           // 7.68 MB
  unsigned short* xb = (unsigned short*)(ws + 7760000);     // 10.24 MB
  unsigned short* featb = (unsigned short*)(ws + 18004096); // 5.12 MB (bf16)
  _Float16* p_pad = (_Float16*)(ws + 23124992);             // 2.56 MB (fp16)
  float* asum_pad = (float*)(ws + 25690112);                // 5.12 MB
  unsigned short* Wpb = (unsigned short*)(ws + 30810112);   // 512 KB
  unsigned short* Gb = (unsigned short*)(ws + 31334400);    // 128 KB
  float* v = (float*)(ws + 31465472);                       // 1 KB
  float* bb = (float*)(ws + 31466496);                      // 1 KB
  unsigned short* Wtp = (unsigned short*)(ws + 31467520);   // 512 KB
  unsigned short* Wtf = (unsigned short*)(ws + 31991808);   // 64 KB
  unsigned short* pT = (unsigned short*)(ws + 32057344);    // 20*64*1024*2 = 2.62 MB

  hipMemsetAsync(deg, 0, 80000, stream);
  hipMemsetAsync(d_out, 0, (size_t)out_size * sizeof(float), stream);

  k_prep<<<4422, 256, 0, stream>>>(h, Wf, Wp, bp, src, dst, deg, ssrc, xb, Wtp, Wtf, Wpb, v, bb);
  k_mid<<<1266, 256, 0, stream>>>(Wpb, Gb, deg, ssrc, xb);
  k_fused<<<625, 256, 0, stream>>>(xb, Gb, Wtp, Wtf, bp, bf, v, bb, featb, p_pad, pT);
  k_as<<<625, 256, 0, stream>>>(p_pad, deg, ssrc, asum_pad);
  k_final<<<NBG, 256, 0, stream>>>(pT, featb, asum_pad, out);
}